// Round 21
// baseline (154.237 us; speedup 1.0000x reference)
//
#include <hip/hip_runtime.h>
#include <hip/hip_bf16.h>
#include <math.h>

#define T_SEQ 2048
#define HID 2048
#define HQ 16
#define HKV 8
#define D_HEAD 128
#define HALF 64
#define SCALE_F 0.08838834764831845f
#define PROJW 4096   // proj row width: q(2048) | k(1024) | v(1024)

typedef __attribute__((ext_vector_type(8))) short bf16x8;
typedef __attribute__((ext_vector_type(4))) float f32x4;

static __device__ __forceinline__ short f2bf(float x) {
  unsigned u = __builtin_bit_cast(unsigned, x);
  unsigned r = (u + 0x7FFF + ((u >> 16) & 1)) >> 16;   // RNE
  return (short)r;
}
static __device__ __forceinline__ float bf2f(unsigned short u) {
  unsigned v = ((unsigned)u) << 16;
  return __builtin_bit_cast(float, v);
}

#define GLDS(gsrc, ldst) \
  __builtin_amdgcn_global_load_lds((const __attribute__((address_space(1))) void*)(gsrc), \
                                   (__attribute__((address_space(3))) void*)(ldst), 16, 0, 0)

// ------- fused transpose of all 4 weights fp32[K][N] -> bf16[N][2048] -------
__global__ __launch_bounds__(256)
void transpose_all(const float* __restrict__ Wq, const float* __restrict__ Wk,
                   const float* __restrict__ Wv, const float* __restrict__ Wo,
                   short* __restrict__ BTall, short* __restrict__ WoT)
{
  const int bx = blockIdx.x;
  const int k0 = blockIdx.y * 32;
  const float* src; short* dst; int Nsrc, n0;
  if (bx < 64)       { src = Wq; Nsrc = 2048; dst = BTall;                       n0 = bx * 32; }
  else if (bx < 96)  { src = Wk; Nsrc = 1024; dst = BTall + (size_t)2048 * 2048; n0 = (bx - 64) * 32; }
  else if (bx < 128) { src = Wv; Nsrc = 1024; dst = BTall + (size_t)3072 * 2048; n0 = (bx - 96) * 32; }
  else               { src = Wo; Nsrc = 2048; dst = WoT;                         n0 = (bx - 128) * 32; }

  __shared__ float tile[32][33];
  const int r = threadIdx.x >> 5, c = threadIdx.x & 31;
  #pragma unroll
  for (int i = 0; i < 4; ++i)
    tile[r + i * 8][c] = src[(size_t)(k0 + r + i * 8) * Nsrc + n0 + c];
  __syncthreads();
  const int n = threadIdx.x >> 3, k4 = (threadIdx.x & 7) * 4;
  short4 o;
  o.x = f2bf(tile[k4 + 0][n]); o.y = f2bf(tile[k4 + 1][n]);
  o.z = f2bf(tile[k4 + 2][n]); o.w = f2bf(tile[k4 + 3][n]);
  *reinterpret_cast<short4*>(&dst[(size_t)(n0 + n) * 2048 + k0 + k4]) = o;
}

// ---------------- fp32 add: out += part ----------------
__global__ __launch_bounds__(256)
void add_f32(float* __restrict__ out, const float* __restrict__ part, int n4)
{
  int i = blockIdx.x * blockDim.x + threadIdx.x;
  if (i >= n4) return;
  float4 a = reinterpret_cast<float4*>(out)[i];
  const float4 b = reinterpret_cast<const float4*>(part)[i];
  a.x += b.x; a.y += b.y; a.z += b.z; a.w += b.w;
  reinterpret_cast<float4*>(out)[i] = a;
}

// ======== bf16 MFMA GEMM: pure-__syncthreads, GROUP-amortized barriers ========
// 128x128 tile, 256 threads (4 waves 2x2, 4x4 frags). 2*GRP LDS buffers in
// groups of GRP BK=32 k-tiles: per iteration, stage the next group into the
// other buffer half (disjoint), compute all GRP k-steps (GRP*16 MFMA), then ONE
// __syncthreads. R20 measured GRP=2 (64 KB, 2 blk/CU): 138->128 us total —
// validates m233's barrier-drain model. GRP=4 (128 KB, 1 blk/CU) tests whether
// amortization beats the occupancy loss (m132 vs m233). Accumulation order
// identical across GRP -> identical numerics.
// split-K via blockIdx.z: z==0 -> Cout0 (+3-way bias), z>0 -> Cout1 fp32.
template <bool OBF, int GRP>
__global__ __launch_bounds__(256)
void gemm_bf16(const short* __restrict__ A, const short* __restrict__ BT,
               const float* __restrict__ b0, const float* __restrict__ b1,
               const float* __restrict__ b2, int s1, int s2,
               void* __restrict__ Cout0, void* __restrict__ Cout1,
               int N, int Kst, int klen)
{
  __shared__ short As[2 * GRP][128 * 32];
  __shared__ short Bs[2 * GRP][128 * 32];
  const int tid = threadIdx.x;
  const int wave = tid >> 6, lane = tid & 63;
  const int bm0 = blockIdx.y * 128, bn0 = blockIdx.x * 128;
  const int z = blockIdx.z;
  const int koff = z * klen;
  const int wm = (wave >> 1) * 64, wn = (wave & 1) * 64;

  const int srow = wave * 32 + (lane >> 2);
  const int scol = (lane & 3) * 8;
  const short* Abase = A + (size_t)(bm0 + srow) * Kst + koff + scol;
  const short* Bbase = BT + (size_t)(bn0 + srow) * Kst + koff + scol;

  f32x4 acc[4][4] = {};

  const int ng = klen / (32 * GRP);   // number of k-tile groups
#define STAGE(buf, kk)                                                           \
  do {                                                                           \
    GLDS(Abase + ((kk) << 5), &As[buf][(wave * 32) * 32]);                       \
    GLDS(Abase + ((kk) << 5) + (size_t)16 * Kst, &As[buf][(wave * 32 + 16) * 32]); \
    GLDS(Bbase + ((kk) << 5), &Bs[buf][(wave * 32) * 32]);                       \
    GLDS(Bbase + ((kk) << 5) + (size_t)16 * Kst, &Bs[buf][(wave * 32 + 16) * 32]); \
  } while (0)

  // prologue: stage group 0 (k-tiles 0..GRP-1) into buffers 0..GRP-1
  #pragma unroll
  for (int e = 0; e < GRP; ++e) STAGE(e, e);
  __syncthreads();

  const int kof = (lane >> 4) * 8;
  const int rA = wm + (lane & 15);
  const int rB = wn + (lane & 15);

  for (int pp = 0; pp < ng; ++pp) {
    const int curb = (pp & 1) * GRP;        // current group: buffers curb..curb+GRP-1
    if (pp + 1 < ng) {                      // stage next group into other buffers
      #pragma unroll
      for (int e = 0; e < GRP; ++e) STAGE((curb ^ GRP) + e, (pp + 1) * GRP + e);
    }
    #pragma unroll
    for (int half = 0; half < GRP; ++half) {
      const int cur = curb + half;
      bf16x8 af[4], bfr[4];
      #pragma unroll
      for (int i = 0; i < 4; ++i) {
        af[i]  = *reinterpret_cast<const bf16x8*>(&As[cur][(rA + i * 16) * 32 + kof]);
        bfr[i] = *reinterpret_cast<const bf16x8*>(&Bs[cur][(rB + i * 16) * 32 + kof]);
      }
      #pragma unroll
      for (int i = 0; i < 4; ++i)
        #pragma unroll
        for (int j = 0; j < 4; ++j)
          acc[i][j] = __builtin_amdgcn_mfma_f32_16x16x32_bf16(af[i], bfr[j], acc[i][j], 0, 0, 0);
    }
    __syncthreads();
  }

  void* Cout = z ? Cout1 : Cout0;
  const int crow = wm + (lane >> 4) * 4;
  const int ccol = wn + (lane & 15);
  #pragma unroll
  for (int j = 0; j < 4; ++j) {
    const int col = bn0 + ccol + j * 16;
    float b = 0.f;
    if (z == 0)
      b = (col < s1) ? b0[col] : ((col < s2) ? b1[col - s1] : b2[col - s2]);
    #pragma unroll
    for (int i = 0; i < 4; ++i)
      #pragma unroll
      for (int r = 0; r < 4; ++r) {
        const int row = bm0 + crow + i * 16 + r;
        const float v = acc[i][j][r] + b;
        if (z == 0) {
          if constexpr (OBF)
            ((short*)Cout)[(size_t)row * N + col] = f2bf(v);
          else
            ((float*)Cout)[(size_t)row * N + col] = v;
        } else {
          ((float*)Cout)[(size_t)row * N + col] = v;
        }
      }
  }
#undef STAGE
}

// ---- gate projection + log-sigmoid, fused with hs -> bf16 conversion ----
__global__ __launch_bounds__(256)
void gproj_kernel(const float* __restrict__ hs, const float* __restrict__ Wg,
                  const float* __restrict__ bg, float* __restrict__ gT,
                  short* __restrict__ hsb)
{
  const int t = blockIdx.x, tid = threadIdx.x;
  __shared__ float red[256][9];
  float a[8] = {0.f, 0.f, 0.f, 0.f, 0.f, 0.f, 0.f, 0.f};
  for (int cc = tid; cc < HID; cc += 256) {
    const float hv = hs[(size_t)t * HID + cc];
    hsb[(size_t)t * HID + cc] = f2bf(hv);        // fused bf16 conversion
    const float4 w0 = *reinterpret_cast<const float4*>(Wg + (size_t)cc * 8);
    const float4 w1 = *reinterpret_cast<const float4*>(Wg + (size_t)cc * 8 + 4);
    a[0] = fmaf(hv, w0.x, a[0]); a[1] = fmaf(hv, w0.y, a[1]);
    a[2] = fmaf(hv, w0.z, a[2]); a[3] = fmaf(hv, w0.w, a[3]);
    a[4] = fmaf(hv, w1.x, a[4]); a[5] = fmaf(hv, w1.y, a[5]);
    a[6] = fmaf(hv, w1.z, a[6]); a[7] = fmaf(hv, w1.w, a[7]);
  }
  #pragma unroll
  for (int j = 0; j < 8; ++j) red[tid][j] = a[j];
  __syncthreads();
  for (int s = 128; s >= 1; s >>= 1) {
    if (tid < s) {
      #pragma unroll
      for (int j = 0; j < 8; ++j) red[tid][j] += red[tid + s][j];
    }
    __syncthreads();
  }
  if (tid < 8) {
    const float x = red[0][tid] + bg[tid];
    const float nx = -x;
    const float sp = (nx > 20.f) ? nx : log1pf(expf(nx));
    gT[(size_t)tid * T_SEQ + t] = -sp;      // log_sigmoid(x)
  }
}

// ------- parallel inclusive cumsum over T per head -------
__global__ __launch_bounds__(512)
void gscan_kernel(const float* __restrict__ gT, float* __restrict__ Gct)
{
  const int h = blockIdx.x;
  const int tid = threadIdx.x;
  const int wid = tid >> 6, lane = tid & 63;
  __shared__ float wsum[8];

  const float4 v = reinterpret_cast<const float4*>(gT + (size_t)h * T_SEQ)[tid];
  const float p0 = v.x, p1 = p0 + v.y, p2 = p1 + v.z, p3 = p2 + v.w;

  float sc = p3;
  #pragma unroll
  for (int off = 1; off < 64; off <<= 1) {
    const float o = __shfl_up(sc, off, 64);
    if (lane >= off) sc += o;
  }
  if (lane == 63) wsum[wid] = sc;
  __syncthreads();
  float wof = 0.f;
  #pragma unroll
  for (int w = 0; w < 8; ++w) wof += (w < wid) ? wsum[w] : 0.f;

  const float excl = wof + sc - p3;
  reinterpret_cast<float4*>(Gct + (size_t)h * T_SEQ)[tid] =
      make_float4(excl + p0, excl + p1, excl + p2, excl + p3);
}

// ---- fused RoPE (blocks 0..2047) + V transpose (blocks 2048..4095) ----
__global__ __launch_bounds__(256)
void rope_vtrans(short* __restrict__ proj, unsigned short* __restrict__ vt)
{
  __shared__ float cs[64], sn[64];
  __shared__ unsigned short tile[32][33];

  if (blockIdx.x < 2048) {
    const int t = blockIdx.x;
    if (threadIdx.x < 64) {
      const int i = threadIdx.x;
      const float f = (float)t * powf(10000.0f, -(float)i / 64.0f);
      cs[i] = cosf(f); sn[i] = sinf(f);
    }
    __syncthreads();
    const int u = threadIdx.x;          // 24 heads x 8 chunks (192 active)
    if (u < 192) {
      const int hh = u >> 3, ch = u & 7;
      short* base = proj + (size_t)t * PROJW +
                    ((hh < HQ) ? hh * D_HEAD : 2048 + (hh - HQ) * D_HEAD);
      bf16x8 x1 = *reinterpret_cast<bf16x8*>(base + ch * 8);
      bf16x8 x2 = *reinterpret_cast<bf16x8*>(base + HALF + ch * 8);
      #pragma unroll
      for (int j = 0; j < 8; ++j) {
        const float a = bf2f((unsigned short)x1[j]);
        const float b = bf2f((unsigned short)x2[j]);
        const float cc = cs[ch * 8 + j], ss = sn[ch * 8 + j];
        x1[j] = f2bf(a * cc - b * ss);
        x2[j] = f2bf(b * cc + a * ss);
      }
      *reinterpret_cast<bf16x8*>(base + ch * 8) = x1;
      *reinterpret_cast<bf16x8*>(base + HALF + ch * 8) = x2;
    }
  } else {
    const int idx = blockIdx.x - 2048;
    const int tt = (idx & 63) * 32, dd = ((idx >> 6) & 3) * 32, hk = idx >> 8;
    const unsigned short* pj = (const unsigned short*)proj;
    const int c = threadIdx.x & 31, r0 = (threadIdx.x >> 5) * 4;
    #pragma unroll
    for (int i = 0; i < 4; ++i)
      tile[r0 + i][c] = pj[(size_t)(tt + r0 + i) * PROJW + 3072 + hk * 128 + dd + c];
    __syncthreads();
    #pragma unroll
    for (int i = 0; i < 4; ++i)
      vt[(size_t)(hk * 128 + dd + r0 + i) * T_SEQ + tt + c] = tile[c][r0 + i];
  }
}

// ---------------- MFMA attention (R11-proven, unchanged) ----------------
__global__ __launch_bounds__(256, 1)
void attn_mfma(const short* __restrict__ proj, const short* __restrict__ vt,
               const float* __restrict__ Gct, short* __restrict__ outb)
{
  __shared__ __align__(16) char smem[86528];
  const int hk = blockIdx.x;
  const int tb = blockIdx.y * 64;
  const int tid = threadIdx.x;
  const int wid = tid >> 6, lane = tid & 63;
  const int c = lane & 15, g = lane >> 4;
  const int h = 2 * hk + (wid >> 1);
  const int tw = tb + (wid & 1) * 32;
  const float* Gh = Gct + (size_t)hk * T_SEQ;

  const float glim = Gh[tb] + 90.0f;
  int lo = 0, hi = tb;
  while (lo < hi) {
    const int mid = (lo + hi) >> 1;
    if (Gh[mid] > glim) lo = mid + 1; else hi = mid;
  }
  const int sfirst = lo & ~63;
  const int nst = ((tb - sfirst) >> 6) + 1;

  bf16x8 qf[2][4];
  #pragma unroll
  for (int tt = 0; tt < 2; ++tt)
    #pragma unroll
    for (int kb = 0; kb < 4; ++kb)
      qf[tt][kb] = *reinterpret_cast<const bf16x8*>(
          proj + (size_t)(tw + 16 * tt + c) * PROJW + h * D_HEAD + kb * 32 + g * 8);
  const float gt0 = Gh[tw + c];
  const float gt1 = Gh[tw + 16 + c];
  const float gtw = Gh[tw];
  const int twmax = tw + 31;

  f32x4 accv[2][8] = {};

#define ASTG(buf, s64)                                                                   \
  do {                                                                                   \
    _Pragma("unroll")                                                                    \
    for (int i2 = 0; i2 < 4; ++i2) {                                                     \
      const int cid = tid + 256 * i2;                                                    \
      const int kr = cid >> 4, kc = cid & 15;                                            \
      GLDS(proj + (size_t)((s64) + kr) * PROJW + 2048 + hk * 128 + ((kc ^ (kr & 7)) * 8),\
           smem + (buf) * 16384 + cid * 16);                                             \
      const int vr = cid >> 3, vc = cid & 7;                                             \
      GLDS(vt + (size_t)(hk * 128 + vr) * T_SEQ + (s64) + ((vc ^ (vr & 7)) * 8),         \
           smem + 32768 + (buf) * 16384 + cid * 16);                                     \
    }                                                                                    \
    if (tid < 64) ((float*)(smem + 86016))[(buf) * 64 + tid] = Gh[(s64) + tid];          \
  } while (0)

  ASTG(0, sfirst);
  __syncthreads();

  for (int i = 0; i < nst; ++i) {
    const int cur = i & 1;
    if (i + 1 < nst) ASTG(cur ^ 1, sfirst + (i + 1) * 64);
    const int sbase64 = sfirst + i * 64;
    const float* Gss = (const float*)(smem + 86016) + cur * 64;
    char* Pmy = smem + 65536 + wid * 5120;

    #pragma unroll
    for (int st = 0; st < 2; ++st) {
      const int s0 = sbase64 + st * 32;
      if (s0 > twmax) continue;
      if (gtw - Gss[st * 32 + 31] < -90.0f) continue;

      bf16x8 kf[2][4];
      #pragma unroll
      for (int sg = 0; sg < 2; ++sg)
        #pragma unroll
        for (int kb = 0; kb < 4; ++kb) {
          const int row = st * 32 + 16 * sg + c;
          const int byt = (row * 256 + kb * 64 + g * 16) ^ ((c & 7) << 4);
          kf[sg][kb] = *reinterpret_cast<const bf16x8*>(smem + cur * 16384 + byt);
        }
      f32x4 sa[2][2] = {};
      #pragma unroll
      for (int kb = 0; kb < 4; ++kb)
        #pragma unroll
        for (int sg = 0; sg < 2; ++sg)
          #pragma unroll
          for (int tt = 0; tt < 2; ++tt)
            sa[sg][tt] = __builtin_amdgcn_mfma_f32_16x16x32_bf16(
                kf[sg][kb], qf[tt][kb], sa[sg][tt], 0, 0, 0);

      #pragma unroll
      for (int sg = 0; sg < 2; ++sg) {
        const float4 gs = *reinterpret_cast<const float4*>(&Gss[st * 32 + sg * 16 + g * 4]);
        const float gsv[4] = {gs.x, gs.y, gs.z, gs.w};
        #pragma unroll
        for (int tt = 0; tt < 2; ++tt) {
          const int tg = tw + 16 * tt + c;
          const float gt = tt ? gt1 : gt0;
          const int sg0 = s0 + sg * 16 + g * 4;
          float w[4];
          #pragma unroll
          for (int r = 0; r < 4; ++r) {
            const float dv = sa[sg][tt][r] * SCALE_F;
            const float ww = dv * dv * __expf(gt - gsv[r]);
            w[r] = (sg0 + r <= tg) ? ww : 0.0f;
          }
          uint2 pv;
          pv.x = ((unsigned)(unsigned short)f2bf(w[1]) << 16) | (unsigned short)f2bf(w[0]);
          pv.y = ((unsigned)(unsigned short)f2bf(w[3]) << 16) | (unsigned short)f2bf(w[2]);
          *reinterpret_cast<uint2*>(Pmy + st * 2560 + (c + 16 * tt) * 80 + 8 * g + 32 * sg) = pv;
        }
      }
      asm volatile("s_waitcnt lgkmcnt(0)" ::: "memory");
      __builtin_amdgcn_sched_barrier(0);

      bf16x8 pf[2];
      #pragma unroll
      for (int tt = 0; tt < 2; ++tt)
        pf[tt] = *reinterpret_cast<const bf16x8*>(Pmy + st * 2560 + (c + 16 * tt) * 80 + g * 16);

      #pragma unroll
      for (int db = 0; db < 8; ++db) {
        const int row = 16 * db + c;
        const int byt = (row * 128 + st * 64 + g * 16) ^ ((c & 7) << 4);
        const bf16x8 vf = *reinterpret_cast<const bf16x8*>(smem + 32768 + cur * 16384 + byt);
        #pragma unroll
        for (int tt = 0; tt < 2; ++tt)
          accv[tt][db] = __builtin_amdgcn_mfma_f32_16x16x32_bf16(pf[tt], vf, accv[tt][db], 0, 0, 0);
      }
    }
    __syncthreads();
  }

  char* Wme = smem + wid * 8704;
  #pragma unroll
  for (int tt = 0; tt < 2; ++tt)
    #pragma unroll
    for (int db = 0; db < 8; ++db)
      #pragma unroll
      for (int r = 0; r < 4; ++r)
        *reinterpret_cast<short*>(Wme + (16 * tt + 4 * g + r) * 272 + (16 * db + c) * 2)
            = f2bf(accv[tt][db][r]);
  asm volatile("s_waitcnt lgkmcnt(0)" ::: "memory");
  __builtin_amdgcn_sched_barrier(0);
  #pragma unroll
  for (int e = 0; e < 8; ++e) {
    const int idx = e * 64 + lane;
    const int tr = idx >> 4, d0 = (idx & 15) * 8;
    const bf16x8 vv = *reinterpret_cast<const bf16x8*>(Wme + tr * 272 + d0 * 2);
    *reinterpret_cast<bf16x8*>(outb + ((size_t)(tw + tr) * HQ + h) * D_HEAD + d0) = vv;
  }
#undef ASTG
}

extern "C" void kernel_launch(void* const* d_in, const int* in_sizes, int n_in,
                              void* d_out, int out_size, void* d_ws, size_t ws_size,
                              hipStream_t stream)
{
  const float* hs = (const float*)d_in[1];
  const float* Wq = (const float*)d_in[2];
  const float* bq = (const float*)d_in[3];
  const float* Wk = (const float*)d_in[4];
  const float* bk = (const float*)d_in[5];
  const float* Wv = (const float*)d_in[6];
  const float* bv = (const float*)d_in[7];
  const float* Wg = (const float*)d_in[8];
  const float* bg = (const float*)d_in[9];
  const float* Wo = (const float*)d_in[10];
  const float* bo = (const float*)d_in[11];
  float* outp = (float*)d_out;

  // workspace carve (~52.2 MB, R11/R15-proven)
  short* proj  = (short*)d_ws;                    // [T][4096] bf16           16 MB
  short* vtb   = proj + (size_t)T_SEQ * PROJW;    // [8][128][T] bf16          4 MB
  float* gT    = (float*)(vtb + (size_t)HKV * D_HEAD * T_SEQ);
  float* Gct   = gT + 16384;
  short* hsb   = (short*)(Gct + 16384);           // [T][2048] bf16            8 MB
  short* BTall = hsb + (size_t)2048 * 2048;       // [4096][2048] bf16        16 MB
  short* WoT   = BTall + (size_t)4096 * 2048;     // [2048][2048] bf16         8 MB
  short* attnout = hsb;                           // alias: hsb dead after QKV GEMM
  float* opart   = (float*)BTall;                 // alias: BTall dead after QKV GEMM

  // 1) weight transposes
  transpose_all<<<dim3(192, 64), 256, 0, stream>>>(Wq, Wk, Wv, Wo, BTall, WoT);

  // 2) gate projection (+ fused hs->bf16) and cumsum scan
  gproj_kernel<<<2048, 256, 0, stream>>>(hs, Wg, bg, gT, hsb);
  gscan_kernel<<<8, 512, 0, stream>>>(gT, Gct);

  // 3) fused QKV projection: 32x16 = 512 blocks, QUAD-amortized barriers (A/B test)
  gemm_bf16<true, 4><<<dim3(32, 16, 1), 256, 0, stream>>>(
      hsb, BTall, bq, bk, bv, 2048, 3072, proj, proj, PROJW, 2048, 2048);

  // 4) fused RoPE + V transpose (one dispatch)
  rope_vtrans<<<4096, 256, 0, stream>>>(proj, (unsigned short*)vtb);

  // 5) attention -> bf16 into hsb region
  attn_mfma<<<dim3(8, 32), 256, 0, stream>>>(proj, vtb, Gct, attnout);

  // 6) output projection, split-K=2, PAIR-amortized (R20-proven): 512 blocks;
  //    z=1 fp32 partial into dead BTall region, then fold.
  gemm_bf16<false, 2><<<dim3(16, 16, 2), 256, 0, stream>>>(
      attnout, WoT, bo, bo, bo, 1 << 30, 1 << 30, outp, opart, 2048, 2048, 1024);
  add_f32<<<4096, 256, 0, stream>>>(outp, opart, 1048576);
}

// Round 22
// 127.356 us; speedup vs baseline: 1.2111x; 1.2111x over previous
//
#include <hip/hip_runtime.h>
#include <hip/hip_bf16.h>
#include <math.h>

#define T_SEQ 2048
#define HID 2048
#define HQ 16
#define HKV 8
#define D_HEAD 128
#define HALF 64
#define SCALE_F 0.08838834764831845f
#define PROJW 4096   // proj row width: q(2048) | k(1024) | v(1024)

typedef __attribute__((ext_vector_type(8))) short bf16x8;
typedef __attribute__((ext_vector_type(4))) float f32x4;

static __device__ __forceinline__ short f2bf(float x) {
  unsigned u = __builtin_bit_cast(unsigned, x);
  unsigned r = (u + 0x7FFF + ((u >> 16) & 1)) >> 16;   // RNE
  return (short)r;
}
static __device__ __forceinline__ float bf2f(unsigned short u) {
  unsigned v = ((unsigned)u) << 16;
  return __builtin_bit_cast(float, v);
}

#define GLDS(gsrc, ldst) \
  __builtin_amdgcn_global_load_lds((const __attribute__((address_space(1))) void*)(gsrc), \
                                   (__attribute__((address_space(3))) void*)(ldst), 16, 0, 0)

// ------- fused transpose of all 4 weights fp32[K][N] -> bf16[N][2048] -------
__global__ __launch_bounds__(256)
void transpose_all(const float* __restrict__ Wq, const float* __restrict__ Wk,
                   const float* __restrict__ Wv, const float* __restrict__ Wo,
                   short* __restrict__ BTall, short* __restrict__ WoT)
{
  const int bx = blockIdx.x;
  const int k0 = blockIdx.y * 32;
  const float* src; short* dst; int Nsrc, n0;
  if (bx < 64)       { src = Wq; Nsrc = 2048; dst = BTall;                       n0 = bx * 32; }
  else if (bx < 96)  { src = Wk; Nsrc = 1024; dst = BTall + (size_t)2048 * 2048; n0 = (bx - 64) * 32; }
  else if (bx < 128) { src = Wv; Nsrc = 1024; dst = BTall + (size_t)3072 * 2048; n0 = (bx - 96) * 32; }
  else               { src = Wo; Nsrc = 2048; dst = WoT;                         n0 = (bx - 128) * 32; }

  __shared__ float tile[32][33];
  const int r = threadIdx.x >> 5, c = threadIdx.x & 31;
  #pragma unroll
  for (int i = 0; i < 4; ++i)
    tile[r + i * 8][c] = src[(size_t)(k0 + r + i * 8) * Nsrc + n0 + c];
  __syncthreads();
  const int n = threadIdx.x >> 3, k4 = (threadIdx.x & 7) * 4;
  short4 o;
  o.x = f2bf(tile[k4 + 0][n]); o.y = f2bf(tile[k4 + 1][n]);
  o.z = f2bf(tile[k4 + 2][n]); o.w = f2bf(tile[k4 + 3][n]);
  *reinterpret_cast<short4*>(&dst[(size_t)(n0 + n) * 2048 + k0 + k4]) = o;
}

// ---------------- fp32 add: out += part ----------------
__global__ __launch_bounds__(256)
void add_f32(float* __restrict__ out, const float* __restrict__ part, int n4)
{
  int i = blockIdx.x * blockDim.x + threadIdx.x;
  if (i >= n4) return;
  float4 a = reinterpret_cast<float4*>(out)[i];
  const float4 b = reinterpret_cast<const float4*>(part)[i];
  a.x += b.x; a.y += b.y; a.z += b.z; a.w += b.w;
  reinterpret_cast<float4*>(out)[i] = a;
}

// ======== bf16 MFMA GEMM: pure-__syncthreads, GROUP-amortized barriers ========
// 128x128 tile, 256 threads (4 waves 2x2, 4x4 frags). 2*GRP LDS buffers in
// groups of GRP BK=32 k-tiles: stage next group into the other buffer half
// (disjoint), compute all GRP k-steps, ONE __syncthreads.
// GRP sweep measured: GRP=1 -> 138 us total | GRP=2 (64 KB, 2 blk/CU) -> 128 us
// (OPTIMUM: halves m233's barrier-drain while keeping 2 co-resident blocks) |
// GRP=4 (128 KB, 1 blk/CU) -> 154 us (m132 occupancy loss dominates).
// split-K via blockIdx.z: z==0 -> Cout0 (+3-way bias), z>0 -> Cout1 fp32.
template <bool OBF, int GRP>
__global__ __launch_bounds__(256)
void gemm_bf16(const short* __restrict__ A, const short* __restrict__ BT,
               const float* __restrict__ b0, const float* __restrict__ b1,
               const float* __restrict__ b2, int s1, int s2,
               void* __restrict__ Cout0, void* __restrict__ Cout1,
               int N, int Kst, int klen)
{
  __shared__ short As[2 * GRP][128 * 32];
  __shared__ short Bs[2 * GRP][128 * 32];
  const int tid = threadIdx.x;
  const int wave = tid >> 6, lane = tid & 63;
  const int bm0 = blockIdx.y * 128, bn0 = blockIdx.x * 128;
  const int z = blockIdx.z;
  const int koff = z * klen;
  const int wm = (wave >> 1) * 64, wn = (wave & 1) * 64;

  const int srow = wave * 32 + (lane >> 2);
  const int scol = (lane & 3) * 8;
  const short* Abase = A + (size_t)(bm0 + srow) * Kst + koff + scol;
  const short* Bbase = BT + (size_t)(bn0 + srow) * Kst + koff + scol;

  f32x4 acc[4][4] = {};

  const int ng = klen / (32 * GRP);   // number of k-tile groups
#define STAGE(buf, kk)                                                           \
  do {                                                                           \
    GLDS(Abase + ((kk) << 5), &As[buf][(wave * 32) * 32]);                       \
    GLDS(Abase + ((kk) << 5) + (size_t)16 * Kst, &As[buf][(wave * 32 + 16) * 32]); \
    GLDS(Bbase + ((kk) << 5), &Bs[buf][(wave * 32) * 32]);                       \
    GLDS(Bbase + ((kk) << 5) + (size_t)16 * Kst, &Bs[buf][(wave * 32 + 16) * 32]); \
  } while (0)

  // prologue: stage group 0 (k-tiles 0..GRP-1) into buffers 0..GRP-1
  #pragma unroll
  for (int e = 0; e < GRP; ++e) STAGE(e, e);
  __syncthreads();

  const int kof = (lane >> 4) * 8;
  const int rA = wm + (lane & 15);
  const int rB = wn + (lane & 15);

  for (int pp = 0; pp < ng; ++pp) {
    const int curb = (pp & 1) * GRP;        // current group: buffers curb..curb+GRP-1
    if (pp + 1 < ng) {                      // stage next group into other buffers
      #pragma unroll
      for (int e = 0; e < GRP; ++e) STAGE((curb ^ GRP) + e, (pp + 1) * GRP + e);
    }
    #pragma unroll
    for (int half = 0; half < GRP; ++half) {
      const int cur = curb + half;
      bf16x8 af[4], bfr[4];
      #pragma unroll
      for (int i = 0; i < 4; ++i) {
        af[i]  = *reinterpret_cast<const bf16x8*>(&As[cur][(rA + i * 16) * 32 + kof]);
        bfr[i] = *reinterpret_cast<const bf16x8*>(&Bs[cur][(rB + i * 16) * 32 + kof]);
      }
      #pragma unroll
      for (int i = 0; i < 4; ++i)
        #pragma unroll
        for (int j = 0; j < 4; ++j)
          acc[i][j] = __builtin_amdgcn_mfma_f32_16x16x32_bf16(af[i], bfr[j], acc[i][j], 0, 0, 0);
    }
    __syncthreads();
  }

  void* Cout = z ? Cout1 : Cout0;
  const int crow = wm + (lane >> 4) * 4;
  const int ccol = wn + (lane & 15);
  #pragma unroll
  for (int j = 0; j < 4; ++j) {
    const int col = bn0 + ccol + j * 16;
    float b = 0.f;
    if (z == 0)
      b = (col < s1) ? b0[col] : ((col < s2) ? b1[col - s1] : b2[col - s2]);
    #pragma unroll
    for (int i = 0; i < 4; ++i)
      #pragma unroll
      for (int r = 0; r < 4; ++r) {
        const int row = bm0 + crow + i * 16 + r;
        const float v = acc[i][j][r] + b;
        if (z == 0) {
          if constexpr (OBF)
            ((short*)Cout)[(size_t)row * N + col] = f2bf(v);
          else
            ((float*)Cout)[(size_t)row * N + col] = v;
        } else {
          ((float*)Cout)[(size_t)row * N + col] = v;
        }
      }
  }
#undef STAGE
}

// ---- gate projection + log-sigmoid, fused with hs -> bf16 conversion ----
__global__ __launch_bounds__(256)
void gproj_kernel(const float* __restrict__ hs, const float* __restrict__ Wg,
                  const float* __restrict__ bg, float* __restrict__ gT,
                  short* __restrict__ hsb)
{
  const int t = blockIdx.x, tid = threadIdx.x;
  __shared__ float red[256][9];
  float a[8] = {0.f, 0.f, 0.f, 0.f, 0.f, 0.f, 0.f, 0.f};
  for (int cc = tid; cc < HID; cc += 256) {
    const float hv = hs[(size_t)t * HID + cc];
    hsb[(size_t)t * HID + cc] = f2bf(hv);        // fused bf16 conversion
    const float4 w0 = *reinterpret_cast<const float4*>(Wg + (size_t)cc * 8);
    const float4 w1 = *reinterpret_cast<const float4*>(Wg + (size_t)cc * 8 + 4);
    a[0] = fmaf(hv, w0.x, a[0]); a[1] = fmaf(hv, w0.y, a[1]);
    a[2] = fmaf(hv, w0.z, a[2]); a[3] = fmaf(hv, w0.w, a[3]);
    a[4] = fmaf(hv, w1.x, a[4]); a[5] = fmaf(hv, w1.y, a[5]);
    a[6] = fmaf(hv, w1.z, a[6]); a[7] = fmaf(hv, w1.w, a[7]);
  }
  #pragma unroll
  for (int j = 0; j < 8; ++j) red[tid][j] = a[j];
  __syncthreads();
  for (int s = 128; s >= 1; s >>= 1) {
    if (tid < s) {
      #pragma unroll
      for (int j = 0; j < 8; ++j) red[tid][j] += red[tid + s][j];
    }
    __syncthreads();
  }
  if (tid < 8) {
    const float x = red[0][tid] + bg[tid];
    const float nx = -x;
    const float sp = (nx > 20.f) ? nx : log1pf(expf(nx));
    gT[(size_t)tid * T_SEQ + t] = -sp;      // log_sigmoid(x)
  }
}

// ------- parallel inclusive cumsum over T per head -------
__global__ __launch_bounds__(512)
void gscan_kernel(const float* __restrict__ gT, float* __restrict__ Gct)
{
  const int h = blockIdx.x;
  const int tid = threadIdx.x;
  const int wid = tid >> 6, lane = tid & 63;
  __shared__ float wsum[8];

  const float4 v = reinterpret_cast<const float4*>(gT + (size_t)h * T_SEQ)[tid];
  const float p0 = v.x, p1 = p0 + v.y, p2 = p1 + v.z, p3 = p2 + v.w;

  float sc = p3;
  #pragma unroll
  for (int off = 1; off < 64; off <<= 1) {
    const float o = __shfl_up(sc, off, 64);
    if (lane >= off) sc += o;
  }
  if (lane == 63) wsum[wid] = sc;
  __syncthreads();
  float wof = 0.f;
  #pragma unroll
  for (int w = 0; w < 8; ++w) wof += (w < wid) ? wsum[w] : 0.f;

  const float excl = wof + sc - p3;
  reinterpret_cast<float4*>(Gct + (size_t)h * T_SEQ)[tid] =
      make_float4(excl + p0, excl + p1, excl + p2, excl + p3);
}

// ---- fused RoPE (blocks 0..2047) + V transpose (blocks 2048..4095) ----
__global__ __launch_bounds__(256)
void rope_vtrans(short* __restrict__ proj, unsigned short* __restrict__ vt)
{
  __shared__ float cs[64], sn[64];
  __shared__ unsigned short tile[32][33];

  if (blockIdx.x < 2048) {
    const int t = blockIdx.x;
    if (threadIdx.x < 64) {
      const int i = threadIdx.x;
      const float f = (float)t * powf(10000.0f, -(float)i / 64.0f);
      cs[i] = cosf(f); sn[i] = sinf(f);
    }
    __syncthreads();
    const int u = threadIdx.x;          // 24 heads x 8 chunks (192 active)
    if (u < 192) {
      const int hh = u >> 3, ch = u & 7;
      short* base = proj + (size_t)t * PROJW +
                    ((hh < HQ) ? hh * D_HEAD : 2048 + (hh - HQ) * D_HEAD);
      bf16x8 x1 = *reinterpret_cast<bf16x8*>(base + ch * 8);
      bf16x8 x2 = *reinterpret_cast<bf16x8*>(base + HALF + ch * 8);
      #pragma unroll
      for (int j = 0; j < 8; ++j) {
        const float a = bf2f((unsigned short)x1[j]);
        const float b = bf2f((unsigned short)x2[j]);
        const float cc = cs[ch * 8 + j], ss = sn[ch * 8 + j];
        x1[j] = f2bf(a * cc - b * ss);
        x2[j] = f2bf(b * cc + a * ss);
      }
      *reinterpret_cast<bf16x8*>(base + ch * 8) = x1;
      *reinterpret_cast<bf16x8*>(base + HALF + ch * 8) = x2;
    }
  } else {
    const int idx = blockIdx.x - 2048;
    const int tt = (idx & 63) * 32, dd = ((idx >> 6) & 3) * 32, hk = idx >> 8;
    const unsigned short* pj = (const unsigned short*)proj;
    const int c = threadIdx.x & 31, r0 = (threadIdx.x >> 5) * 4;
    #pragma unroll
    for (int i = 0; i < 4; ++i)
      tile[r0 + i][c] = pj[(size_t)(tt + r0 + i) * PROJW + 3072 + hk * 128 + dd + c];
    __syncthreads();
    #pragma unroll
    for (int i = 0; i < 4; ++i)
      vt[(size_t)(hk * 128 + dd + r0 + i) * T_SEQ + tt + c] = tile[c][r0 + i];
  }
}

// ---------------- MFMA attention (R11-proven, unchanged) ----------------
__global__ __launch_bounds__(256, 1)
void attn_mfma(const short* __restrict__ proj, const short* __restrict__ vt,
               const float* __restrict__ Gct, short* __restrict__ outb)
{
  __shared__ __align__(16) char smem[86528];
  const int hk = blockIdx.x;
  const int tb = blockIdx.y * 64;
  const int tid = threadIdx.x;
  const int wid = tid >> 6, lane = tid & 63;
  const int c = lane & 15, g = lane >> 4;
  const int h = 2 * hk + (wid >> 1);
  const int tw = tb + (wid & 1) * 32;
  const float* Gh = Gct + (size_t)hk * T_SEQ;

  const float glim = Gh[tb] + 90.0f;
  int lo = 0, hi = tb;
  while (lo < hi) {
    const int mid = (lo + hi) >> 1;
    if (Gh[mid] > glim) lo = mid + 1; else hi = mid;
  }
  const int sfirst = lo & ~63;
  const int nst = ((tb - sfirst) >> 6) + 1;

  bf16x8 qf[2][4];
  #pragma unroll
  for (int tt = 0; tt < 2; ++tt)
    #pragma unroll
    for (int kb = 0; kb < 4; ++kb)
      qf[tt][kb] = *reinterpret_cast<const bf16x8*>(
          proj + (size_t)(tw + 16 * tt + c) * PROJW + h * D_HEAD + kb * 32 + g * 8);
  const float gt0 = Gh[tw + c];
  const float gt1 = Gh[tw + 16 + c];
  const float gtw = Gh[tw];
  const int twmax = tw + 31;

  f32x4 accv[2][8] = {};

#define ASTG(buf, s64)                                                                   \
  do {                                                                                   \
    _Pragma("unroll")                                                                    \
    for (int i2 = 0; i2 < 4; ++i2) {                                                     \
      const int cid = tid + 256 * i2;                                                    \
      const int kr = cid >> 4, kc = cid & 15;                                            \
      GLDS(proj + (size_t)((s64) + kr) * PROJW + 2048 + hk * 128 + ((kc ^ (kr & 7)) * 8),\
           smem + (buf) * 16384 + cid * 16);                                             \
      const int vr = cid >> 3, vc = cid & 7;                                             \
      GLDS(vt + (size_t)(hk * 128 + vr) * T_SEQ + (s64) + ((vc ^ (vr & 7)) * 8),         \
           smem + 32768 + (buf) * 16384 + cid * 16);                                     \
    }                                                                                    \
    if (tid < 64) ((float*)(smem + 86016))[(buf) * 64 + tid] = Gh[(s64) + tid];          \
  } while (0)

  ASTG(0, sfirst);
  __syncthreads();

  for (int i = 0; i < nst; ++i) {
    const int cur = i & 1;
    if (i + 1 < nst) ASTG(cur ^ 1, sfirst + (i + 1) * 64);
    const int sbase64 = sfirst + i * 64;
    const float* Gss = (const float*)(smem + 86016) + cur * 64;
    char* Pmy = smem + 65536 + wid * 5120;

    #pragma unroll
    for (int st = 0; st < 2; ++st) {
      const int s0 = sbase64 + st * 32;
      if (s0 > twmax) continue;
      if (gtw - Gss[st * 32 + 31] < -90.0f) continue;

      bf16x8 kf[2][4];
      #pragma unroll
      for (int sg = 0; sg < 2; ++sg)
        #pragma unroll
        for (int kb = 0; kb < 4; ++kb) {
          const int row = st * 32 + 16 * sg + c;
          const int byt = (row * 256 + kb * 64 + g * 16) ^ ((c & 7) << 4);
          kf[sg][kb] = *reinterpret_cast<const bf16x8*>(smem + cur * 16384 + byt);
        }
      f32x4 sa[2][2] = {};
      #pragma unroll
      for (int kb = 0; kb < 4; ++kb)
        #pragma unroll
        for (int sg = 0; sg < 2; ++sg)
          #pragma unroll
          for (int tt = 0; tt < 2; ++tt)
            sa[sg][tt] = __builtin_amdgcn_mfma_f32_16x16x32_bf16(
                kf[sg][kb], qf[tt][kb], sa[sg][tt], 0, 0, 0);

      #pragma unroll
      for (int sg = 0; sg < 2; ++sg) {
        const float4 gs = *reinterpret_cast<const float4*>(&Gss[st * 32 + sg * 16 + g * 4]);
        const float gsv[4] = {gs.x, gs.y, gs.z, gs.w};
        #pragma unroll
        for (int tt = 0; tt < 2; ++tt) {
          const int tg = tw + 16 * tt + c;
          const float gt = tt ? gt1 : gt0;
          const int sg0 = s0 + sg * 16 + g * 4;
          float w[4];
          #pragma unroll
          for (int r = 0; r < 4; ++r) {
            const float dv = sa[sg][tt][r] * SCALE_F;
            const float ww = dv * dv * __expf(gt - gsv[r]);
            w[r] = (sg0 + r <= tg) ? ww : 0.0f;
          }
          uint2 pv;
          pv.x = ((unsigned)(unsigned short)f2bf(w[1]) << 16) | (unsigned short)f2bf(w[0]);
          pv.y = ((unsigned)(unsigned short)f2bf(w[3]) << 16) | (unsigned short)f2bf(w[2]);
          *reinterpret_cast<uint2*>(Pmy + st * 2560 + (c + 16 * tt) * 80 + 8 * g + 32 * sg) = pv;
        }
      }
      asm volatile("s_waitcnt lgkmcnt(0)" ::: "memory");
      __builtin_amdgcn_sched_barrier(0);

      bf16x8 pf[2];
      #pragma unroll
      for (int tt = 0; tt < 2; ++tt)
        pf[tt] = *reinterpret_cast<const bf16x8*>(Pmy + st * 2560 + (c + 16 * tt) * 80 + g * 16);

      #pragma unroll
      for (int db = 0; db < 8; ++db) {
        const int row = 16 * db + c;
        const int byt = (row * 128 + st * 64 + g * 16) ^ ((c & 7) << 4);
        const bf16x8 vf = *reinterpret_cast<const bf16x8*>(smem + 32768 + cur * 16384 + byt);
        #pragma unroll
        for (int tt = 0; tt < 2; ++tt)
          accv[tt][db] = __builtin_amdgcn_mfma_f32_16x16x32_bf16(pf[tt], vf, accv[tt][db], 0, 0, 0);
      }
    }
    __syncthreads();
  }

  char* Wme = smem + wid * 8704;
  #pragma unroll
  for (int tt = 0; tt < 2; ++tt)
    #pragma unroll
    for (int db = 0; db < 8; ++db)
      #pragma unroll
      for (int r = 0; r < 4; ++r)
        *reinterpret_cast<short*>(Wme + (16 * tt + 4 * g + r) * 272 + (16 * db + c) * 2)
            = f2bf(accv[tt][db][r]);
  asm volatile("s_waitcnt lgkmcnt(0)" ::: "memory");
  __builtin_amdgcn_sched_barrier(0);
  #pragma unroll
  for (int e = 0; e < 8; ++e) {
    const int idx = e * 64 + lane;
    const int tr = idx >> 4, d0 = (idx & 15) * 8;
    const bf16x8 vv = *reinterpret_cast<const bf16x8*>(Wme + tr * 272 + d0 * 2);
    *reinterpret_cast<bf16x8*>(outb + ((size_t)(tw + tr) * HQ + h) * D_HEAD + d0) = vv;
  }
#undef ASTG
}

extern "C" void kernel_launch(void* const* d_in, const int* in_sizes, int n_in,
                              void* d_out, int out_size, void* d_ws, size_t ws_size,
                              hipStream_t stream)
{
  const float* hs = (const float*)d_in[1];
  const float* Wq = (const float*)d_in[2];
  const float* bq = (const float*)d_in[3];
  const float* Wk = (const float*)d_in[4];
  const float* bk = (const float*)d_in[5];
  const float* Wv = (const float*)d_in[6];
  const float* bv = (const float*)d_in[7];
  const float* Wg = (const float*)d_in[8];
  const float* bg = (const float*)d_in[9];
  const float* Wo = (const float*)d_in[10];
  const float* bo = (const float*)d_in[11];
  float* outp = (float*)d_out;

  // workspace carve (~52.2 MB, R11/R15-proven)
  short* proj  = (short*)d_ws;                    // [T][4096] bf16           16 MB
  short* vtb   = proj + (size_t)T_SEQ * PROJW;    // [8][128][T] bf16          4 MB
  float* gT    = (float*)(vtb + (size_t)HKV * D_HEAD * T_SEQ);
  float* Gct   = gT + 16384;
  short* hsb   = (short*)(Gct + 16384);           // [T][2048] bf16            8 MB
  short* BTall = hsb + (size_t)2048 * 2048;       // [4096][2048] bf16        16 MB
  short* WoT   = BTall + (size_t)4096 * 2048;     // [2048][2048] bf16         8 MB
  short* attnout = hsb;                           // alias: hsb dead after QKV GEMM
  float* opart   = (float*)BTall;                 // alias: BTall dead after QKV GEMM

  // 1) weight transposes
  transpose_all<<<dim3(192, 64), 256, 0, stream>>>(Wq, Wk, Wv, Wo, BTall, WoT);

  // 2) gate projection (+ fused hs->bf16) and cumsum scan
  gproj_kernel<<<2048, 256, 0, stream>>>(hs, Wg, bg, gT, hsb);
  gscan_kernel<<<8, 512, 0, stream>>>(gT, Gct);

  // 3) fused QKV projection: 32x16 = 512 blocks, PAIR-amortized (GRP=2, R20-optimum)
  gemm_bf16<true, 2><<<dim3(32, 16, 1), 256, 0, stream>>>(
      hsb, BTall, bq, bk, bv, 2048, 3072, proj, proj, PROJW, 2048, 2048);

  // 4) fused RoPE + V transpose (one dispatch)
  rope_vtrans<<<4096, 256, 0, stream>>>(proj, (unsigned short*)vtb);

  // 5) attention -> bf16 into hsb region
  attn_mfma<<<dim3(8, 32), 256, 0, stream>>>(proj, vtb, Gct, attnout);

  // 6) output projection, split-K=2, PAIR-amortized (GRP=2): 512 blocks;
  //    z=1 fp32 partial into dead BTall region, then fold.
  gemm_bf16<false, 2><<<dim3(16, 16, 2), 256, 0, stream>>>(
      attnout, WoT, bo, bo, bo, 1 << 30, 1 << 30, outp, opart, 2048, 2048, 1024);
  add_f32<<<4096, 256, 0, stream>>>(outp, opart, 1048576);
}